// Round 1
// baseline (300.381 us; speedup 1.0000x reference)
//
#include <hip/hip_runtime.h>

#define Bb 8
#define Cc 256
#define C4 64
#define Nn 4096

typedef short short8 __attribute__((ext_vector_type(8)));
typedef float f32x4 __attribute__((ext_vector_type(4)));

__device__ __forceinline__ unsigned short f2bf(float f) {
  unsigned int u = __float_as_uint(f);
  return (unsigned short)((u + 0x7FFFu + ((u >> 16) & 1u)) >> 16);
}
__device__ __forceinline__ float bf2f(unsigned short h) {
  return __uint_as_float(((unsigned int)h) << 16);
}
__device__ __forceinline__ f32x4 fz4() {
  f32x4 z; z[0] = 0.f; z[1] = 0.f; z[2] = 0.f; z[3] = 0.f; return z;
}

// ---------------- K0: weight prep (bf16 + hi/lo split for w_qk) ----------------
__global__ void k0_weights(const float* __restrict__ wqk, const float* __restrict__ wv,
                           const float* __restrict__ wt,
                           unsigned short* __restrict__ wqk_hi, unsigned short* __restrict__ wqk_lo,
                           unsigned short* __restrict__ wv_bf, unsigned short* __restrict__ wt_bf) {
  int idx = blockIdx.x * 256 + threadIdx.x;
  if (idx < C4 * Cc) {
    float f = wqk[idx];
    unsigned short h = f2bf(f);
    wqk_hi[idx] = h;
    wqk_lo[idx] = f2bf(f - bf2f(h));
  }
  if (idx < Cc * Cc) {
    wv_bf[idx] = f2bf(wv[idx]);
    wt_bf[idx] = f2bf(wt[idx]);
  }
}

// ---------------- K23: qk (split hi/lo) + x_v  ----------------
// qk_hi/lo: [b][n][64] bf16   xvb: [b][c][n] bf16
__global__ __launch_bounds__(512) void k23_qkv(
    const float* __restrict__ x,
    const unsigned short* __restrict__ wqk_hi, const unsigned short* __restrict__ wqk_lo,
    const unsigned short* __restrict__ wv_bf, const float* __restrict__ bv,
    unsigned short* __restrict__ qk_hi, unsigned short* __restrict__ qk_lo,
    unsigned short* __restrict__ xvb) {
  __shared__ unsigned short xh[64 * 264];  // [n][c] transposed x, hi
  __shared__ unsigned short xl[64 * 264];  // lo
  const int b = blockIdx.y, n0 = blockIdx.x * 64, tid = threadIdx.x;
  {
    const int cc = tid >> 3, nn = (tid & 7) * 8;
    #pragma unroll
    for (int ph = 0; ph < 4; ++ph) {
      int c = cc + ph * 64;
      const float* src = x + ((size_t)(b * Cc + c)) * Nn + n0 + nn;
      float4 v0 = *(const float4*)(src);
      float4 v1 = *(const float4*)(src + 4);
      float vv[8] = {v0.x, v0.y, v0.z, v0.w, v1.x, v1.y, v1.z, v1.w};
      #pragma unroll
      for (int j = 0; j < 8; ++j) {
        unsigned short h = f2bf(vv[j]);
        xh[(nn + j) * 264 + c] = h;
        xl[(nn + j) * 264 + c] = f2bf(vv[j] - bf2f(h));
      }
    }
  }
  __syncthreads();
  const int w = tid >> 6, lane = tid & 63, l15 = lane & 15, l4 = lane >> 4;
  // ---- qk: out [64 n][64 o], K=256 (c), split 3-term ----
  {
    const int fn = w >> 1, ob = (w & 1) * 32;
    f32x4 acc[2] = {fz4(), fz4()};
    #pragma unroll
    for (int kb = 0; kb < 8; ++kb) {
      const int k = kb * 32 + l4 * 8;
      short8 ah = *(const short8*)(xh + (fn * 16 + l15) * 264 + k);
      short8 al = *(const short8*)(xl + (fn * 16 + l15) * 264 + k);
      #pragma unroll
      for (int f = 0; f < 2; ++f) {
        const int o = ob + f * 16 + l15;
        short8 bh = *(const short8*)(wqk_hi + o * Cc + k);
        short8 bl = *(const short8*)(wqk_lo + o * Cc + k);
        acc[f] = __builtin_amdgcn_mfma_f32_16x16x32_bf16(ah, bh, acc[f], 0, 0, 0);
        acc[f] = __builtin_amdgcn_mfma_f32_16x16x32_bf16(ah, bl, acc[f], 0, 0, 0);
        acc[f] = __builtin_amdgcn_mfma_f32_16x16x32_bf16(al, bh, acc[f], 0, 0, 0);
      }
    }
    #pragma unroll
    for (int f = 0; f < 2; ++f) {
      #pragma unroll
      for (int i = 0; i < 4; ++i) {
        const int n = n0 + fn * 16 + l4 * 4 + i;
        const int o = ob + f * 16 + l15;
        float v = acc[f][i];
        unsigned short h = f2bf(v);
        qk_hi[((size_t)b * Nn + n) * C4 + o] = h;
        qk_lo[((size_t)b * Nn + n) * C4 + o] = f2bf(v - bf2f(h));
      }
    }
  }
  // ---- x_v: out [256 c][64 n], K=256 ----
  {
    const int cb = w * 32;
    f32x4 acc[2][4];
    #pragma unroll
    for (int a = 0; a < 2; ++a)
      #pragma unroll
      for (int q = 0; q < 4; ++q) acc[a][q] = fz4();
    #pragma unroll
    for (int kb = 0; kb < 8; ++kb) {
      const int k = kb * 32 + l4 * 8;
      short8 bfr[4];
      #pragma unroll
      for (int fnb = 0; fnb < 4; ++fnb)
        bfr[fnb] = *(const short8*)(xh + (fnb * 16 + l15) * 264 + k);
      #pragma unroll
      for (int fc = 0; fc < 2; ++fc) {
        const int c = cb + fc * 16 + l15;
        short8 a = *(const short8*)(wv_bf + c * Cc + k);
        #pragma unroll
        for (int fnb = 0; fnb < 4; ++fnb)
          acc[fc][fnb] = __builtin_amdgcn_mfma_f32_16x16x32_bf16(a, bfr[fnb], acc[fc][fnb], 0, 0, 0);
      }
    }
    #pragma unroll
    for (int fc = 0; fc < 2; ++fc)
      #pragma unroll
      for (int fnb = 0; fnb < 4; ++fnb)
        #pragma unroll
        for (int i = 0; i < 4; ++i) {
          const int c = cb + fc * 16 + l4 * 4 + i;
          const int n = n0 + fnb * 16 + l15;
          float v = acc[fc][fnb][i] + bv[c];
          xvb[((size_t)b * Cc + c) * Nn + n] = f2bf(v);
        }
  }
}

// ---------------- K4: softmax row stats  a_n = 64 + log(sum_m exp(E[n][m]-64)) ----------------
__global__ __launch_bounds__(512) void k4_stats(
    const unsigned short* __restrict__ qk_hi, const unsigned short* __restrict__ qk_lo,
    float* __restrict__ stats) {
  __shared__ unsigned short qnh[128 * 72], qnl[128 * 72];
  __shared__ unsigned short qmh[64 * 72], qml[64 * 72];
  __shared__ float red[128 * 2];
  const int b = blockIdx.y, n0 = blockIdx.x * 128, tid = threadIdx.x;
  #pragma unroll
  for (int p = 0; p < 2; ++p) {
    int u = tid + 512 * p, r = u >> 3, blk = u & 7;
    *(short8*)(qnh + r * 72 + blk * 8) =
        *(const short8*)(qk_hi + ((size_t)b * Nn + n0 + r) * C4 + blk * 8);
    *(short8*)(qnl + r * 72 + blk * 8) =
        *(const short8*)(qk_lo + ((size_t)b * Nn + n0 + r) * C4 + blk * 8);
  }
  __syncthreads();
  const int w = tid >> 6, lane = tid & 63, l15 = lane & 15, l4 = lane >> 4;
  const int wn = w >> 1, wm = w & 1;
  float sm[2][4];
  #pragma unroll
  for (int a = 0; a < 2; ++a)
    #pragma unroll
    for (int i = 0; i < 4; ++i) sm[a][i] = 0.f;
  for (int it = 0; it < 64; ++it) {
    {
      int r = tid >> 3, blk = tid & 7;
      *(short8*)(qmh + r * 72 + blk * 8) =
          *(const short8*)(qk_hi + ((size_t)b * Nn + it * 64 + r) * C4 + blk * 8);
      *(short8*)(qml + r * 72 + blk * 8) =
          *(const short8*)(qk_lo + ((size_t)b * Nn + it * 64 + r) * C4 + blk * 8);
    }
    __syncthreads();
    f32x4 acc[2][2];
    #pragma unroll
    for (int a = 0; a < 2; ++a)
      #pragma unroll
      for (int q = 0; q < 2; ++q) acc[a][q] = fz4();
    #pragma unroll
    for (int kb = 0; kb < 2; ++kb) {
      const int k = kb * 32 + l4 * 8;
      #pragma unroll
      for (int fn = 0; fn < 2; ++fn) {
        short8 ah = *(const short8*)(qnh + (wn * 32 + fn * 16 + l15) * 72 + k);
        short8 al = *(const short8*)(qnl + (wn * 32 + fn * 16 + l15) * 72 + k);
        #pragma unroll
        for (int fm = 0; fm < 2; ++fm) {
          short8 bh = *(const short8*)(qmh + (wm * 32 + fm * 16 + l15) * 72 + k);
          short8 bl = *(const short8*)(qml + (wm * 32 + fm * 16 + l15) * 72 + k);
          acc[fn][fm] = __builtin_amdgcn_mfma_f32_16x16x32_bf16(ah, bh, acc[fn][fm], 0, 0, 0);
          acc[fn][fm] = __builtin_amdgcn_mfma_f32_16x16x32_bf16(ah, bl, acc[fn][fm], 0, 0, 0);
          acc[fn][fm] = __builtin_amdgcn_mfma_f32_16x16x32_bf16(al, bh, acc[fn][fm], 0, 0, 0);
        }
      }
    }
    #pragma unroll
    for (int fn = 0; fn < 2; ++fn)
      #pragma unroll
      for (int fm = 0; fm < 2; ++fm)
        #pragma unroll
        for (int i = 0; i < 4; ++i)
          sm[fn][i] += __expf(acc[fn][fm][i] - 64.0f);
    __syncthreads();
  }
  #pragma unroll
  for (int msk = 1; msk < 16; msk <<= 1)
    #pragma unroll
    for (int fn = 0; fn < 2; ++fn)
      #pragma unroll
      for (int i = 0; i < 4; ++i)
        sm[fn][i] += __shfl_xor(sm[fn][i], msk, 64);
  if (l15 == 0) {
    #pragma unroll
    for (int fn = 0; fn < 2; ++fn)
      #pragma unroll
      for (int i = 0; i < 4; ++i) {
        int r = wn * 32 + fn * 16 + l4 * 4 + i;
        red[r * 2 + wm] = sm[fn][i];
      }
  }
  __syncthreads();
  if (tid < 128) {
    float t = red[tid * 2] + red[tid * 2 + 1];
    stats[(size_t)b * Nn + n0 + tid] = 64.0f + __logf(t);
  }
}

// ---------------- K5: fused attention-apply + conv_t + BN + ReLU + residual ----------------
__global__ __launch_bounds__(512) void k5_main(
    const float* __restrict__ x,
    const unsigned short* __restrict__ qk_hi, const unsigned short* __restrict__ qk_lo,
    const unsigned short* __restrict__ xvb, const float* __restrict__ stats,
    const unsigned short* __restrict__ wt_bf, const float* __restrict__ bt,
    const float* __restrict__ gamma, const float* __restrict__ beta,
    const float* __restrict__ rmean, const float* __restrict__ rvar,
    float* __restrict__ out) {
  __shared__ __align__(16) char smem[137216];
  unsigned short* qmh = (unsigned short*)smem;           // [128*72]
  unsigned short* qml = qmh + 128 * 72;                  // +18432 -> 36864
  float* aL = (float*)(smem + 36864);                    // 4096 f32 -> 53248
  unsigned short* qnh = (unsigned short*)(smem + 53248); // [64*72]
  unsigned short* qnl = qnh + 64 * 72;                   // 62464
  unsigned short* PT = qnl + 64 * 72;                    // 71680 [128*72]
  unsigned short* xvp = PT + 128 * 72;                   // 90112 [256*72] -> 126976
  const int b = blockIdx.y, m0 = blockIdx.x * 128, tid = threadIdx.x;
  #pragma unroll
  for (int p = 0; p < 2; ++p) {
    int u = tid + 512 * p, r = u >> 3, blk = u & 7;
    *(short8*)(qmh + r * 72 + blk * 8) =
        *(const short8*)(qk_hi + ((size_t)b * Nn + m0 + r) * C4 + blk * 8);
    *(short8*)(qml + r * 72 + blk * 8) =
        *(const short8*)(qk_lo + ((size_t)b * Nn + m0 + r) * C4 + blk * 8);
  }
  for (int i = tid; i < Nn; i += 512) aL[i] = stats[(size_t)b * Nn + i];

  const int w = tid >> 6, lane = tid & 63, l15 = lane & 15, l4 = lane >> 4;
  const int wm = w >> 2;  // 0..1  (m block *64)
  const int wc = w & 3;   // 0..3  (c block *64 in PV, n quarter *16 in G)
  f32x4 acc[4][4];
  #pragma unroll
  for (int a = 0; a < 4; ++a)
    #pragma unroll
    for (int q = 0; q < 4; ++q) acc[a][q] = fz4();

  for (int it = 0; it < 64; ++it) {
    __syncthreads();  // A: previous PV reads done
    {
      int r = tid >> 3, blk = tid & 7;
      *(short8*)(qnh + r * 72 + blk * 8) =
          *(const short8*)(qk_hi + ((size_t)b * Nn + it * 64 + r) * C4 + blk * 8);
      *(short8*)(qnl + r * 72 + blk * 8) =
          *(const short8*)(qk_lo + ((size_t)b * Nn + it * 64 + r) * C4 + blk * 8);
    }
    #pragma unroll
    for (int p = 0; p < 4; ++p) {
      int u = tid + 512 * p, r = u >> 3, blk = u & 7;
      *(short8*)(xvp + r * 72 + blk * 8) =
          *(const short8*)(xvb + ((size_t)b * Cc + r) * Nn + it * 64 + blk * 8);
    }
    __syncthreads();  // B: staging visible
    // G = qm . qn  (split 3-term), out [128 m][64 n]; this wave: m wm*64, n wc*16
    f32x4 g[4];
    #pragma unroll
    for (int q = 0; q < 4; ++q) g[q] = fz4();
    #pragma unroll
    for (int kb = 0; kb < 2; ++kb) {
      const int k = kb * 32 + l4 * 8;
      short8 bh = *(const short8*)(qnh + (wc * 16 + l15) * 72 + k);
      short8 bl = *(const short8*)(qnl + (wc * 16 + l15) * 72 + k);
      #pragma unroll
      for (int fm = 0; fm < 4; ++fm) {
        short8 ah = *(const short8*)(qmh + (wm * 64 + fm * 16 + l15) * 72 + k);
        short8 al = *(const short8*)(qml + (wm * 64 + fm * 16 + l15) * 72 + k);
        g[fm] = __builtin_amdgcn_mfma_f32_16x16x32_bf16(ah, bh, g[fm], 0, 0, 0);
        g[fm] = __builtin_amdgcn_mfma_f32_16x16x32_bf16(ah, bl, g[fm], 0, 0, 0);
        g[fm] = __builtin_amdgcn_mfma_f32_16x16x32_bf16(al, bh, g[fm], 0, 0, 0);
      }
    }
    const float an = aL[it * 64 + wc * 16 + l15];
    #pragma unroll
    for (int fm = 0; fm < 4; ++fm)
      #pragma unroll
      for (int i = 0; i < 4; ++i) {
        float pv = __expf(g[fm][i] - an);
        PT[(wm * 64 + fm * 16 + l4 * 4 + i) * 72 + wc * 16 + l15] = f2bf(pv);
      }
    __syncthreads();  // C: PT complete
    // x_r^T[m][c] += PT[m][n] * xv[c][n]
    #pragma unroll
    for (int kb = 0; kb < 2; ++kb) {
      const int k = kb * 32 + l4 * 8;
      short8 pa[4], xb[4];
      #pragma unroll
      for (int fm = 0; fm < 4; ++fm)
        pa[fm] = *(const short8*)(PT + (wm * 64 + fm * 16 + l15) * 72 + k);
      #pragma unroll
      for (int fc = 0; fc < 4; ++fc)
        xb[fc] = *(const short8*)(xvp + (wc * 64 + fc * 16 + l15) * 72 + k);
      #pragma unroll
      for (int fm = 0; fm < 4; ++fm)
        #pragma unroll
        for (int fc = 0; fc < 4; ++fc)
          acc[fm][fc] = __builtin_amdgcn_mfma_f32_16x16x32_bf16(pa[fm], xb[fc], acc[fm][fc], 0, 0, 0);
    }
  }
  __syncthreads();
  // Epilogue: s^T = x - x_r^T  (bf16, LDS), then t = w_t . s + b_t, BN, ReLU, +x
  unsigned short* xs = (unsigned short*)smem;            // [256][136] bf16
  unsigned short* st = (unsigned short*)(smem + 69632);  // [128][264] bf16
  #pragma unroll
  for (int p = 0; p < 16; ++p) {
    int u = tid + 512 * p;
    int c = u >> 5, mb = (u & 31) * 4;
    const float* src = x + ((size_t)b * Cc + c) * Nn + m0 + mb;
    float4 v = *(const float4*)src;
    unsigned short* d = xs + c * 136 + mb;
    d[0] = f2bf(v.x); d[1] = f2bf(v.y); d[2] = f2bf(v.z); d[3] = f2bf(v.w);
  }
  __syncthreads();
  #pragma unroll
  for (int fm = 0; fm < 4; ++fm)
    #pragma unroll
    for (int fc = 0; fc < 4; ++fc)
      #pragma unroll
      for (int i = 0; i < 4; ++i) {
        int m = wm * 64 + fm * 16 + l4 * 4 + i;
        int c = wc * 64 + fc * 16 + l15;
        float s = bf2f(xs[c * 136 + m]) - acc[fm][fc][i];
        st[m * 264 + c] = f2bf(s);
      }
  __syncthreads();
  {
    const int ob = (w >> 1) * 64, mb = (w & 1) * 64;
    f32x4 t[4][4];
    #pragma unroll
    for (int a = 0; a < 4; ++a)
      #pragma unroll
      for (int q = 0; q < 4; ++q) t[a][q] = fz4();
    #pragma unroll
    for (int kb = 0; kb < 8; ++kb) {
      const int k = kb * 32 + l4 * 8;
      short8 bfr[4];
      #pragma unroll
      for (int fm = 0; fm < 4; ++fm)
        bfr[fm] = *(const short8*)(st + (mb + fm * 16 + l15) * 264 + k);
      #pragma unroll
      for (int fo = 0; fo < 4; ++fo) {
        short8 a = *(const short8*)(wt_bf + (ob + fo * 16 + l15) * Cc + k);
        #pragma unroll
        for (int fm = 0; fm < 4; ++fm)
          t[fo][fm] = __builtin_amdgcn_mfma_f32_16x16x32_bf16(a, bfr[fm], t[fo][fm], 0, 0, 0);
      }
    }
    #pragma unroll
    for (int fo = 0; fo < 4; ++fo)
      #pragma unroll
      for (int i = 0; i < 4; ++i) {
        const int o = ob + fo * 16 + l4 * 4 + i;
        const float inv = gamma[o] * rsqrtf(rvar[o] + 1e-5f);
        const float addv = beta[o] - rmean[o] * inv;
        const float btv = bt[o];
        #pragma unroll
        for (int fm = 0; fm < 4; ++fm) {
          const int m = m0 + mb + fm * 16 + l15;
          float tv = t[fo][fm][i] + btv;
          float bn = tv * inv + addv;
          float xr = x[((size_t)b * Cc + o) * Nn + m];
          out[((size_t)b * Cc + o) * Nn + m] = xr + fmaxf(bn, 0.0f);
        }
      }
  }
}

extern "C" void kernel_launch(void* const* d_in, const int* in_sizes, int n_in,
                              void* d_out, int out_size, void* d_ws, size_t ws_size,
                              hipStream_t stream) {
  const float* x = (const float*)d_in[0];
  const float* wqk = (const float*)d_in[1];
  const float* wv = (const float*)d_in[2];
  const float* bv = (const float*)d_in[3];
  const float* wt = (const float*)d_in[4];
  const float* bt = (const float*)d_in[5];
  const float* gamma = (const float*)d_in[6];
  const float* beta = (const float*)d_in[7];
  const float* rmean = (const float*)d_in[8];
  const float* rvar = (const float*)d_in[9];
  float* out = (float*)d_out;

  char* ws = (char*)d_ws;
  size_t off = 0;
  auto alloc = [&](size_t nb) {
    char* p = ws + off;
    off += (nb + 255) & ~(size_t)255;
    return p;
  };
  unsigned short* qk_hi = (unsigned short*)alloc((size_t)Bb * Nn * C4 * 2);
  unsigned short* qk_lo = (unsigned short*)alloc((size_t)Bb * Nn * C4 * 2);
  unsigned short* xvb = (unsigned short*)alloc((size_t)Bb * Cc * Nn * 2);
  float* stats = (float*)alloc((size_t)Bb * Nn * 4);
  unsigned short* wqk_hi = (unsigned short*)alloc((size_t)C4 * Cc * 2);
  unsigned short* wqk_lo = (unsigned short*)alloc((size_t)C4 * Cc * 2);
  unsigned short* wv_bf = (unsigned short*)alloc((size_t)Cc * Cc * 2);
  unsigned short* wt_bf = (unsigned short*)alloc((size_t)Cc * Cc * 2);

  k0_weights<<<dim3(256), dim3(256), 0, stream>>>(wqk, wv, wt, wqk_hi, wqk_lo, wv_bf, wt_bf);
  k23_qkv<<<dim3(64, 8), dim3(512), 0, stream>>>(x, wqk_hi, wqk_lo, wv_bf, bv, qk_hi, qk_lo, xvb);
  k4_stats<<<dim3(32, 8), dim3(512), 0, stream>>>(qk_hi, qk_lo, stats);
  k5_main<<<dim3(32, 8), dim3(512), 0, stream>>>(x, qk_hi, qk_lo, xvb, stats, wt_bf, bt,
                                                 gamma, beta, rmean, rvar, out);
}

// Round 2
// 240.334 us; speedup vs baseline: 1.2498x; 1.2498x over previous
//
#include <hip/hip_runtime.h>

#define Bb 8
#define Cc 256
#define C4 64
#define Nn 4096

typedef short short8 __attribute__((ext_vector_type(8)));
typedef float f32x4 __attribute__((ext_vector_type(4)));
typedef unsigned int u32;

__device__ __forceinline__ unsigned short f2bf(float f) {
  unsigned int u = __float_as_uint(f);
  return (unsigned short)((u + 0x7FFFu + ((u >> 16) & 1u)) >> 16);
}
__device__ __forceinline__ float bf2f(unsigned short h) {
  return __uint_as_float(((unsigned int)h) << 16);
}
__device__ __forceinline__ u32 pk2bf(float a, float b) {
  return (u32)f2bf(a) | ((u32)f2bf(b) << 16);
}
__device__ __forceinline__ f32x4 fz4() {
  f32x4 z; z[0] = 0.f; z[1] = 0.f; z[2] = 0.f; z[3] = 0.f; return z;
}
__device__ __forceinline__ void gll16(const void* g, void* l) {
  __builtin_amdgcn_global_load_lds(
      (const __attribute__((address_space(1))) u32*)g,
      (__attribute__((address_space(3))) u32*)l, 16, 0, 0);
}
#define BAR_LGKM()                                          \
  asm volatile("s_waitcnt lgkmcnt(0)" ::: "memory");        \
  __builtin_amdgcn_s_barrier()
#define BAR_VM_LGKM()                                              \
  asm volatile("s_waitcnt vmcnt(0) lgkmcnt(0)" ::: "memory");      \
  __builtin_amdgcn_s_barrier()

// ---------------- K0: weight prep (bf16 + hi/lo split for w_qk) ----------------
__global__ void k0_weights(const float* __restrict__ wqk, const float* __restrict__ wv,
                           const float* __restrict__ wt,
                           unsigned short* __restrict__ wqk_hi, unsigned short* __restrict__ wqk_lo,
                           unsigned short* __restrict__ wv_bf, unsigned short* __restrict__ wt_bf) {
  int idx = blockIdx.x * 256 + threadIdx.x;
  if (idx < C4 * Cc) {
    float f = wqk[idx];
    unsigned short h = f2bf(f);
    wqk_hi[idx] = h;
    wqk_lo[idx] = f2bf(f - bf2f(h));
  }
  if (idx < Cc * Cc) {
    wv_bf[idx] = f2bf(wv[idx]);
    wt_bf[idx] = f2bf(wt[idx]);
  }
}

// ---------------- K23: qk (split hi/lo) + x_v  ----------------
// qk_hi/lo: [b][n][64] bf16   xvb: [b][c][n] bf16
__global__ __launch_bounds__(512) void k23_qkv(
    const float* __restrict__ x,
    const unsigned short* __restrict__ wqk_hi, const unsigned short* __restrict__ wqk_lo,
    const unsigned short* __restrict__ wv_bf, const float* __restrict__ bv,
    unsigned short* __restrict__ qk_hi, unsigned short* __restrict__ qk_lo,
    unsigned short* __restrict__ xvb) {
  __shared__ unsigned short xh[64 * 264];  // [n][c] transposed x, hi
  __shared__ unsigned short xl[64 * 264];  // lo
  const int bid = blockIdx.x;
  const int b = bid & 7, n0 = (bid >> 3) * 64, tid = threadIdx.x;
  {
    const int cc = tid >> 3, nn = (tid & 7) * 8;
    #pragma unroll
    for (int ph = 0; ph < 4; ++ph) {
      int c = cc + ph * 64;
      const float* src = x + ((size_t)(b * Cc + c)) * Nn + n0 + nn;
      float4 v0 = *(const float4*)(src);
      float4 v1 = *(const float4*)(src + 4);
      float vv[8] = {v0.x, v0.y, v0.z, v0.w, v1.x, v1.y, v1.z, v1.w};
      #pragma unroll
      for (int j = 0; j < 8; ++j) {
        unsigned short h = f2bf(vv[j]);
        xh[(nn + j) * 264 + c] = h;
        xl[(nn + j) * 264 + c] = f2bf(vv[j] - bf2f(h));
      }
    }
  }
  __syncthreads();
  const int w = tid >> 6, lane = tid & 63, l15 = lane & 15, l4 = lane >> 4;
  // ---- qk: out [64 n][64 o], K=256 (c), split 3-term ----
  {
    const int fn = w >> 1, ob = (w & 1) * 32;
    f32x4 acc[2] = {fz4(), fz4()};
    #pragma unroll
    for (int kb = 0; kb < 8; ++kb) {
      const int k = kb * 32 + l4 * 8;
      short8 ah = *(const short8*)(xh + (fn * 16 + l15) * 264 + k);
      short8 al = *(const short8*)(xl + (fn * 16 + l15) * 264 + k);
      #pragma unroll
      for (int f = 0; f < 2; ++f) {
        const int o = ob + f * 16 + l15;
        short8 bh = *(const short8*)(wqk_hi + o * Cc + k);
        short8 bl = *(const short8*)(wqk_lo + o * Cc + k);
        acc[f] = __builtin_amdgcn_mfma_f32_16x16x32_bf16(ah, bh, acc[f], 0, 0, 0);
        acc[f] = __builtin_amdgcn_mfma_f32_16x16x32_bf16(ah, bl, acc[f], 0, 0, 0);
        acc[f] = __builtin_amdgcn_mfma_f32_16x16x32_bf16(al, bh, acc[f], 0, 0, 0);
      }
    }
    #pragma unroll
    for (int f = 0; f < 2; ++f) {
      #pragma unroll
      for (int i = 0; i < 4; ++i) {
        const int n = n0 + fn * 16 + l4 * 4 + i;
        const int o = ob + f * 16 + l15;
        float v = acc[f][i];
        unsigned short h = f2bf(v);
        qk_hi[((size_t)b * Nn + n) * C4 + o] = h;
        qk_lo[((size_t)b * Nn + n) * C4 + o] = f2bf(v - bf2f(h));
      }
    }
  }
  // ---- x_v: out [256 c][64 n], K=256 ----
  {
    const int cb = w * 32;
    f32x4 acc[2][4];
    #pragma unroll
    for (int a = 0; a < 2; ++a)
      #pragma unroll
      for (int q = 0; q < 4; ++q) acc[a][q] = fz4();
    #pragma unroll
    for (int kb = 0; kb < 8; ++kb) {
      const int k = kb * 32 + l4 * 8;
      short8 bfr[4];
      #pragma unroll
      for (int fnb = 0; fnb < 4; ++fnb)
        bfr[fnb] = *(const short8*)(xh + (fnb * 16 + l15) * 264 + k);
      #pragma unroll
      for (int fc = 0; fc < 2; ++fc) {
        const int c = cb + fc * 16 + l15;
        short8 a = *(const short8*)(wv_bf + c * Cc + k);
        #pragma unroll
        for (int fnb = 0; fnb < 4; ++fnb)
          acc[fc][fnb] = __builtin_amdgcn_mfma_f32_16x16x32_bf16(a, bfr[fnb], acc[fc][fnb], 0, 0, 0);
      }
    }
    #pragma unroll
    for (int fc = 0; fc < 2; ++fc)
      #pragma unroll
      for (int fnb = 0; fnb < 4; ++fnb)
        #pragma unroll
        for (int i = 0; i < 4; ++i) {
          const int c = cb + fc * 16 + l4 * 4 + i;
          const int n = n0 + fnb * 16 + l15;
          float v = acc[fc][fnb][i] + bv[c];
          xvb[((size_t)b * Cc + c) * Nn + n] = f2bf(v);
        }
  }
}

// ---------------- K4: softmax row stats  a_n = 64 + log(sum_m exp(E[n][m]-64)) ----------------
// qn in registers; qm double-buffered via global_load_lds with XOR-swizzled source.
__global__ __launch_bounds__(512) void k4_stats(
    const unsigned short* __restrict__ qk_hi, const unsigned short* __restrict__ qk_lo,
    float* __restrict__ stats) {
  __shared__ unsigned short qmS[2][2][128 * 64];  // [buf][hi/lo][m][c] linear
  __shared__ float red[128][4];
  const int bid = blockIdx.x;
  const int b = bid & 7, n0 = (bid >> 3) * 128, tid = threadIdx.x;
  const int w = tid >> 6, lane = tid & 63, l15 = lane & 15, l4 = lane >> 4;
  const int wn = w & 1, wm4 = w >> 1;
  const size_t bq4 = (size_t)b * Nn;

  // qn fragments in registers (B operand, rows n)
  short8 qnh_r[2][4], qnl_r[2][4];
  #pragma unroll
  for (int kb = 0; kb < 2; ++kb)
    #pragma unroll
    for (int fb = 0; fb < 4; ++fb) {
      size_t o = (bq4 + n0 + wn * 64 + fb * 16 + l15) * C4 + kb * 32 + l4 * 8;
      qnh_r[kb][fb] = *(const short8*)(qk_hi + o);
      qnl_r[kb][fb] = *(const short8*)(qk_lo + o);
    }

  const int srow = lane >> 3;                 // 0..7
  const int scol = (lane & 7) ^ (lane >> 3);  // swizzled 16B column
  auto stage = [&](int buf, int itx) {
    #pragma unroll
    for (int part = 0; part < 2; ++part) {
      const unsigned short* gsrc = part ? qk_lo : qk_hi;
      #pragma unroll
      for (int j = 0; j < 2; ++j) {
        gll16(gsrc + (bq4 + (size_t)itx * 128 + w * 16 + j * 8 + srow) * C4 + scol * 8,
              (char*)qmS[buf][part] + (w * 16 + j * 8) * 128);
      }
    }
  };
  stage(0, 0);

  float sm[4] = {0.f, 0.f, 0.f, 0.f};
  for (int it = 0; it < 32; ++it) {
    const int buf = it & 1;
    BAR_VM_LGKM();
    int itn = (it + 1 < 32) ? it + 1 : it;
    stage(buf ^ 1, itn);
    f32x4 g[2][4];
    #pragma unroll
    for (int fa = 0; fa < 2; ++fa)
      #pragma unroll
      for (int fb = 0; fb < 4; ++fb) g[fa][fb] = fz4();
    #pragma unroll
    for (int kb = 0; kb < 2; ++kb)
      #pragma unroll
      for (int fa = 0; fa < 2; ++fa) {
        const int m = wm4 * 32 + fa * 16 + l15;
        const u32 addr = (u32)((m * 128 + kb * 64 + l4 * 16) ^ ((l15 & 7) << 4));
        short8 ah = *(const short8*)((const char*)qmS[buf][0] + addr);
        short8 al = *(const short8*)((const char*)qmS[buf][1] + addr);
        #pragma unroll
        for (int fb = 0; fb < 4; ++fb) {
          g[fa][fb] = __builtin_amdgcn_mfma_f32_16x16x32_bf16(ah, qnh_r[kb][fb], g[fa][fb], 0, 0, 0);
          g[fa][fb] = __builtin_amdgcn_mfma_f32_16x16x32_bf16(ah, qnl_r[kb][fb], g[fa][fb], 0, 0, 0);
          g[fa][fb] = __builtin_amdgcn_mfma_f32_16x16x32_bf16(al, qnh_r[kb][fb], g[fa][fb], 0, 0, 0);
        }
      }
    #pragma unroll
    for (int fa = 0; fa < 2; ++fa)
      #pragma unroll
      for (int fb = 0; fb < 4; ++fb)
        #pragma unroll
        for (int i = 0; i < 4; ++i)
          sm[fb] += __expf(g[fa][fb][i] - 64.0f);
  }
  #pragma unroll
  for (int fb = 0; fb < 4; ++fb) {
    sm[fb] += __shfl_xor(sm[fb], 16, 64);
    sm[fb] += __shfl_xor(sm[fb], 32, 64);
  }
  if (l4 == 0) {
    #pragma unroll
    for (int fb = 0; fb < 4; ++fb) red[wn * 64 + fb * 16 + l15][wm4] = sm[fb];
  }
  __syncthreads();
  if (tid < 128) {
    float t = red[tid][0] + red[tid][1] + red[tid][2] + red[tid][3];
    stats[bq4 + n0 + tid] = 64.0f + __logf(t);
  }
}

// ---------------- K5: fused attention-apply + conv_t + BN + ReLU + residual ----------------
// qm in registers; transposed-G (mfma(qn,qm)) for packed PT writes; xv via gll+XOR-swizzle.
__global__ __launch_bounds__(512, 2) void k5_main(
    const float* __restrict__ x,
    const unsigned short* __restrict__ qk_hi, const unsigned short* __restrict__ qk_lo,
    const unsigned short* __restrict__ xvb, const float* __restrict__ stats,
    const unsigned short* __restrict__ wt_bf, const float* __restrict__ bt,
    const float* __restrict__ gamma, const float* __restrict__ beta,
    const float* __restrict__ rmean, const float* __restrict__ rvar,
    float* __restrict__ out) {
  __shared__ __align__(16) char smem[137216];
  unsigned short* qnh = (unsigned short*)smem;             // [128][72]  -> 18432
  unsigned short* qnl = (unsigned short*)(smem + 18432);   // -> 36864
  unsigned short* PT  = (unsigned short*)(smem + 36864);   // [128 m][136 n] -> 71680
  unsigned short* xvL = (unsigned short*)(smem + 71680);   // [256 c][128 n] linear -> 137216
  const int bid = blockIdx.x;
  const int b = bid & 7, m0 = (bid >> 3) * 128, tid = threadIdx.x;
  const int w = tid >> 6, lane = tid & 63, l15 = lane & 15, l4 = lane >> 4;
  const int wm = w >> 2;  // 0..1  m-64 block
  const int wn = w & 3;   // 0..3  n-32 block (G) / c-64 block (PV)
  const size_t bq4 = (size_t)b * Nn;
  const size_t sb = bq4;  // stats base

  // qm fragments in registers (B operand, rows m), hi/lo
  short8 qmh_r[2][4], qml_r[2][4];
  #pragma unroll
  for (int kb = 0; kb < 2; ++kb)
    #pragma unroll
    for (int fm = 0; fm < 4; ++fm) {
      size_t o = (bq4 + m0 + wm * 64 + fm * 16 + l15) * C4 + kb * 32 + l4 * 8;
      qmh_r[kb][fm] = *(const short8*)(qk_hi + o);
      qml_r[kb][fm] = *(const short8*)(qk_lo + o);
    }

  // qn staging registers (T14): loaded for it=0 here
  short8 sqh[2], sql[2];
  #pragma unroll
  for (int p = 0; p < 2; ++p) {
    int ci = tid + 512 * p, row = ci >> 3, blk = ci & 7;
    sqh[p] = *(const short8*)(qk_hi + (bq4 + row) * C4 + blk * 8);
    sql[p] = *(const short8*)(qk_lo + (bq4 + row) * C4 + blk * 8);
  }

  f32x4 acc[4][4];
  #pragma unroll
  for (int a = 0; a < 4; ++a)
    #pragma unroll
    for (int q = 0; q < 4; ++q) acc[a][q] = fz4();

  const unsigned short* xvbb = xvb + (size_t)b * Cc * Nn;

  for (int it = 0; it < 32; ++it) {
    // A: previous iteration's LDS reads complete
    BAR_LGKM();
    // issue xv global_load_lds for THIS iter (lands by barrier C)
    #pragma unroll
    for (int j = 0; j < 8; ++j) {
      const int c = w * 32 + j * 4 + (lane >> 4);
      const int col = (lane & 15) ^ (c & 7);
      gll16(xvbb + (size_t)c * Nn + it * 128 + col * 8,
            (char*)xvL + (w * 32 + j * 4) * 256);
    }
    // write qn from staging regs
    #pragma unroll
    for (int p = 0; p < 2; ++p) {
      int ci = tid + 512 * p, row = ci >> 3, blk = ci & 7;
      *(short8*)(qnh + row * 72 + blk * 8) = sqh[p];
      *(short8*)(qnl + row * 72 + blk * 8) = sql[p];
    }
    // B: qn visible
    BAR_LGKM();
    // prefetch qn for it+1 into regs
    {
      int itn = (it + 1 < 32) ? it + 1 : it;
      #pragma unroll
      for (int p = 0; p < 2; ++p) {
        int ci = tid + 512 * p, row = ci >> 3, blk = ci & 7;
        sqh[p] = *(const short8*)(qk_hi + (bq4 + (size_t)itn * 128 + row) * C4 + blk * 8);
        sql[p] = *(const short8*)(qk_lo + (bq4 + (size_t)itn * 128 + row) * C4 + blk * 8);
      }
    }
    // G = qn x qm (transposed: out [n][m]), 3-term split
    f32x4 g[2][4];
    #pragma unroll
    for (int fn = 0; fn < 2; ++fn)
      #pragma unroll
      for (int fm = 0; fm < 4; ++fm) g[fn][fm] = fz4();
    #pragma unroll
    for (int kb = 0; kb < 2; ++kb)
      #pragma unroll
      for (int fn = 0; fn < 2; ++fn) {
        short8 ah = *(const short8*)(qnh + (wn * 32 + fn * 16 + l15) * 72 + kb * 32 + l4 * 8);
        short8 al = *(const short8*)(qnl + (wn * 32 + fn * 16 + l15) * 72 + kb * 32 + l4 * 8);
        #pragma unroll
        for (int fm = 0; fm < 4; ++fm) {
          g[fn][fm] = __builtin_amdgcn_mfma_f32_16x16x32_bf16(ah, qmh_r[kb][fm], g[fn][fm], 0, 0, 0);
          g[fn][fm] = __builtin_amdgcn_mfma_f32_16x16x32_bf16(ah, qml_r[kb][fm], g[fn][fm], 0, 0, 0);
          g[fn][fm] = __builtin_amdgcn_mfma_f32_16x16x32_bf16(al, qmh_r[kb][fm], g[fn][fm], 0, 0, 0);
        }
      }
    // exp + packed PT write:  PT[m][n] = exp(G - a_n), lane holds 4 consecutive n
    #pragma unroll
    for (int fn = 0; fn < 2; ++fn) {
      float4 an = *(const float4*)(stats + sb + (size_t)it * 128 + wn * 32 + fn * 16 + l4 * 4);
      #pragma unroll
      for (int fm = 0; fm < 4; ++fm) {
        float e0 = __expf(g[fn][fm][0] - an.x);
        float e1 = __expf(g[fn][fm][1] - an.y);
        float e2 = __expf(g[fn][fm][2] - an.z);
        float e3 = __expf(g[fn][fm][3] - an.w);
        uint2 pk;
        pk.x = pk2bf(e0, e1);
        pk.y = pk2bf(e2, e3);
        *(uint2*)(PT + (wm * 64 + fm * 16 + l15) * 136 + wn * 32 + fn * 16 + l4 * 4) = pk;
      }
    }
    // C: PT visible + xv gll landed
    BAR_VM_LGKM();
    // PV: x_r^T[m][c] += P[m][n] * xv[c][n]
    #pragma unroll
    for (int kb = 0; kb < 4; ++kb) {
      short8 pa[4], xb[4];
      #pragma unroll
      for (int fm = 0; fm < 4; ++fm)
        pa[fm] = *(const short8*)(PT + (wm * 64 + fm * 16 + l15) * 136 + kb * 32 + l4 * 8);
      #pragma unroll
      for (int fc = 0; fc < 4; ++fc) {
        const int c = wn * 64 + fc * 16 + l15;
        xb[fc] = *(const short8*)((const char*)xvL +
                                  ((c * 256 + kb * 64 + l4 * 16) ^ ((c & 7) << 4)));
      }
      #pragma unroll
      for (int fm = 0; fm < 4; ++fm)
        #pragma unroll
        for (int fc = 0; fc < 4; ++fc)
          acc[fm][fc] = __builtin_amdgcn_mfma_f32_16x16x32_bf16(pa[fm], xb[fc], acc[fm][fc], 0, 0, 0);
    }
  }
  BAR_LGKM();
  // Epilogue: s^T = x - x_r^T  (bf16, LDS), then t = w_t . s + b_t, BN, ReLU, +x
  unsigned short* xs = (unsigned short*)smem;            // [256][136] bf16
  unsigned short* st = (unsigned short*)(smem + 69632);  // [128][264] bf16
  #pragma unroll
  for (int p = 0; p < 16; ++p) {
    int u = tid + 512 * p;
    int c = u >> 5, mb = (u & 31) * 4;
    const float* src = x + ((size_t)b * Cc + c) * Nn + m0 + mb;
    float4 v = *(const float4*)src;
    unsigned short* d = xs + c * 136 + mb;
    d[0] = f2bf(v.x); d[1] = f2bf(v.y); d[2] = f2bf(v.z); d[3] = f2bf(v.w);
  }
  __syncthreads();
  #pragma unroll
  for (int fm = 0; fm < 4; ++fm)
    #pragma unroll
    for (int fc = 0; fc < 4; ++fc)
      #pragma unroll
      for (int i = 0; i < 4; ++i) {
        int m = wm * 64 + fm * 16 + l4 * 4 + i;
        int c = wn * 64 + fc * 16 + l15;
        float s = bf2f(xs[c * 136 + m]) - acc[fm][fc][i];
        st[m * 264 + c] = f2bf(s);
      }
  __syncthreads();
  {
    const int ob = (w >> 1) * 64, mb = (w & 1) * 64;
    f32x4 t[4][4];
    #pragma unroll
    for (int a = 0; a < 4; ++a)
      #pragma unroll
      for (int q = 0; q < 4; ++q) t[a][q] = fz4();
    #pragma unroll
    for (int kb = 0; kb < 8; ++kb) {
      const int k = kb * 32 + l4 * 8;
      short8 bfr[4];
      #pragma unroll
      for (int fm = 0; fm < 4; ++fm)
        bfr[fm] = *(const short8*)(st + (mb + fm * 16 + l15) * 264 + k);
      #pragma unroll
      for (int fo = 0; fo < 4; ++fo) {
        short8 a = *(const short8*)(wt_bf + (ob + fo * 16 + l15) * Cc + k);
        #pragma unroll
        for (int fm = 0; fm < 4; ++fm)
          t[fo][fm] = __builtin_amdgcn_mfma_f32_16x16x32_bf16(a, bfr[fm], t[fo][fm], 0, 0, 0);
      }
    }
    #pragma unroll
    for (int fo = 0; fo < 4; ++fo)
      #pragma unroll
      for (int i = 0; i < 4; ++i) {
        const int o = ob + fo * 16 + l4 * 4 + i;
        const float inv = gamma[o] * rsqrtf(rvar[o] + 1e-5f);
        const float addv = beta[o] - rmean[o] * inv;
        const float btv = bt[o];
        #pragma unroll
        for (int fm = 0; fm < 4; ++fm) {
          const int m = m0 + mb + fm * 16 + l15;
          float tv = t[fo][fm][i] + btv;
          float bn = tv * inv + addv;
          float xr = x[((size_t)b * Cc + o) * Nn + m];
          out[((size_t)b * Cc + o) * Nn + m] = xr + fmaxf(bn, 0.0f);
        }
      }
  }
}

extern "C" void kernel_launch(void* const* d_in, const int* in_sizes, int n_in,
                              void* d_out, int out_size, void* d_ws, size_t ws_size,
                              hipStream_t stream) {
  const float* x = (const float*)d_in[0];
  const float* wqk = (const float*)d_in[1];
  const float* wv = (const float*)d_in[2];
  const float* bv = (const float*)d_in[3];
  const float* wt = (const float*)d_in[4];
  const float* bt = (const float*)d_in[5];
  const float* gamma = (const float*)d_in[6];
  const float* beta = (const float*)d_in[7];
  const float* rmean = (const float*)d_in[8];
  const float* rvar = (const float*)d_in[9];
  float* out = (float*)d_out;

  char* ws = (char*)d_ws;
  size_t off = 0;
  auto alloc = [&](size_t nb) {
    char* p = ws + off;
    off += (nb + 255) & ~(size_t)255;
    return p;
  };
  unsigned short* qk_hi = (unsigned short*)alloc((size_t)Bb * Nn * C4 * 2);
  unsigned short* qk_lo = (unsigned short*)alloc((size_t)Bb * Nn * C4 * 2);
  unsigned short* xvb = (unsigned short*)alloc((size_t)Bb * Cc * Nn * 2);
  float* stats = (float*)alloc((size_t)Bb * Nn * 4);
  unsigned short* wqk_hi = (unsigned short*)alloc((size_t)C4 * Cc * 2);
  unsigned short* wqk_lo = (unsigned short*)alloc((size_t)C4 * Cc * 2);
  unsigned short* wv_bf = (unsigned short*)alloc((size_t)Cc * Cc * 2);
  unsigned short* wt_bf = (unsigned short*)alloc((size_t)Cc * Cc * 2);

  k0_weights<<<dim3(256), dim3(256), 0, stream>>>(wqk, wv, wt, wqk_hi, wqk_lo, wv_bf, wt_bf);
  k23_qkv<<<dim3(512), dim3(512), 0, stream>>>(x, wqk_hi, wqk_lo, wv_bf, bv, qk_hi, qk_lo, xvb);
  k4_stats<<<dim3(256), dim3(512), 0, stream>>>(qk_hi, qk_lo, stats);
  k5_main<<<dim3(256), dim3(512), 0, stream>>>(x, qk_hi, qk_lo, xvb, stats, wt_bf, bt,
                                               gamma, beta, rmean, rvar, out);
}